// Round 9
// baseline (87.462 us; speedup 1.0000x reference)
//
#include <hip/hip_runtime.h>
#include <hip/hip_fp16.h>

#define NNODES 1024
#define NHEADS 8
#define NHID 16
#define DIM 128            // NHEADS * NHID
#define NEG_SLOPE 0.2f
#define XSTRIDE 36         // words per 4-j group in xL (144 B: 16B-aligned, bank-spread)

union F2H { float f; __half2 h; };

// K1: g(fp16) = h @ W^T ; src[i,h] = g·a_src ; dst[i,h] = g·a_dst
__global__ __launch_bounds__(128) void proj_kernel(
    const float* __restrict__ h, const float* __restrict__ W,
    const float* __restrict__ attn_w,
    __half* __restrict__ gh, float* __restrict__ srcv, float* __restrict__ dstv)
{
    const int i = blockIdx.x;
    const int o = threadIdx.x;
    __shared__ float hs[DIM];
    hs[o] = h[(size_t)i * DIM + o];
    __syncthreads();
    const float4* hv = (const float4*)hs;
    const float4* wv = (const float4*)(W + (size_t)o * DIM);
    float acc = 0.f;
#pragma unroll
    for (int k = 0; k < DIM / 4; k++) {
        float4 a = hv[k]; float4 b = wv[k];
        acc = fmaf(a.x, b.x, fmaf(a.y, b.y, fmaf(a.z, b.z, fmaf(a.w, b.w, acc))));
    }
    gh[(size_t)i * DIM + o] = __float2half_rn(acc);
    const int f  = o & (NHID - 1);
    const int hd = o >> 4;
    float sv = acc * attn_w[f];
    float dv = acc * attn_w[NHID + f];
#pragma unroll
    for (int off = 8; off > 0; off >>= 1) {
        sv += __shfl_xor(sv, off, 64);
        dv += __shfl_xor(dv, off, 64);
    }
    if (f == 0) { srcv[i * NHEADS + hd] = sv; dstv[i * NHEADS + hd] = dv; }
}

// K2: one block per 2 rows. A2 stages x=exp(lrelu(src+dst)) as fp16 pairs in LDS;
// B is pure b128 LDS reads + fp16 g loads + 1 exp per weight. No shuffles in B.
__global__ __launch_bounds__(256, 2) void fused_kernel(
    const int* __restrict__ adj, const float* __restrict__ s,
    const __half* __restrict__ gh, const float* __restrict__ srcv,
    const float* __restrict__ dstv, float* __restrict__ out)
{
    const int i0   = blockIdx.x * 2;
    const int tid  = threadIdx.x;
    const int lane = tid & 63;
    const int wv   = tid >> 6;            // wave 0..3

    __shared__ float evL[2][NNODES];          // 8 KB
    __shared__ float xLf[256 * XSTRIDE];      // 36 KB: x pairs, [jg][h][k] words
    __shared__ float sh_src[2][NHEADS];
    __shared__ float zeA[4][NHEADS][2];
    __shared__ float zsA[4][2];
    __shared__ float statE[2][NHEADS];
    __shared__ float statS[2];
    __shared__ float redO[4][2][NHEADS][2][8]; // 4 KB
    __shared__ float ztA[4][2][NHEADS];

    // ---- Phase A1: ev = adj ? exp(s) : 0 into LDS; zs partial ----
    float zs0 = 0.f, zs1 = 0.f;
#pragma unroll
    for (int r = 0; r < 2; r++) {
        const int4   a  = ((const int4*)  adj)[(size_t)(i0 + r) * (NNODES/4) + tid];
        const float4 sv = ((const float4*)s  )[(size_t)(i0 + r) * (NNODES/4) + tid];
        float4 e4;
        e4.x = a.x ? __expf(sv.x) : 0.f;
        e4.y = a.y ? __expf(sv.y) : 0.f;
        e4.z = a.z ? __expf(sv.z) : 0.f;
        e4.w = a.w ? __expf(sv.w) : 0.f;
        ((float4*)evL[r])[tid] = e4;
        const float t = e4.x + e4.y + e4.z + e4.w;
        if (r == 0) zs0 += t; else zs1 += t;
    }
    if (tid < 16) sh_src[tid >> 3][tid & 7] =
        srcv[(size_t)(i0 + (tid >> 3)) * NHEADS + (tid & 7)];
    __syncthreads();

    // ---- Phase A2: x = exp(lrelu(src+dst)) -> xL fp16; ze denominators ----
    const int hA = tid & 7;
    const int jA = tid >> 3;              // 0..31
    const float sA0 = sh_src[0][hA], sA1 = sh_src[1][hA];
    float ze0 = 0.f, ze1 = 0.f;
#pragma unroll 2
    for (int t = 0; t < 8; t++) {
        const int jg = t * 32 + jA;
        const int j0 = jg * 4;
        float dk[4];
#pragma unroll
        for (int k = 0; k < 4; k++) dk[k] = dstv[(size_t)(j0 + k) * NHEADS + hA];
        const float4 e0q = *(const float4*)&evL[0][j0];
        const float4 e1q = *(const float4*)&evL[1][j0];
        const float ev0a[4] = {e0q.x, e0q.y, e0q.z, e0q.w};
        const float ev1a[4] = {e1q.x, e1q.y, e1q.z, e1q.w};
#pragma unroll
        for (int k = 0; k < 4; k++) {
            float e0 = sA0 + dk[k];
            e0 = e0 > 0.f ? e0 : NEG_SLOPE * e0;
            const float x0 = __expf(e0);
            float e1 = sA1 + dk[k];
            e1 = e1 > 0.f ? e1 : NEG_SLOPE * e1;
            const float x1 = __expf(e1);
            ze0 += (ev0a[k] != 0.f) ? x0 : 0.f;
            ze1 += (ev1a[k] != 0.f) ? x1 : 0.f;
            F2H u;
            u.h = __halves2half2(__float2half_rn(x0), __float2half_rn(x1));
            xLf[jg * XSTRIDE + hA * 4 + k] = u.f;
        }
    }
    // reduce ze over jA-in-wave (lane bits 3..5); zs over whole wave
#pragma unroll
    for (int off = 8; off <= 32; off <<= 1) {
        ze0 += __shfl_xor(ze0, off, 64);
        ze1 += __shfl_xor(ze1, off, 64);
    }
#pragma unroll
    for (int off = 1; off <= 32; off <<= 1) {
        zs0 += __shfl_xor(zs0, off, 64);
        zs1 += __shfl_xor(zs1, off, 64);
    }
    if (lane < NHEADS) { zeA[wv][lane][0] = ze0; zeA[wv][lane][1] = ze1; }
    if (lane == 0)     { zsA[wv][0] = zs0; zsA[wv][1] = zs1; }
    __syncthreads();
    if (tid < 16) {
        const int hh = tid & 7, rr = tid >> 3;
        statE[rr][hh] = 1.f / (zeA[0][hh][rr] + zeA[1][hh][rr] +
                               zeA[2][hh][rr] + zeA[3][hh][rr]);
    } else if (tid < 18) {
        const int rr = tid - 16;
        statS[rr] = 1.f / (zsA[0][rr] + zsA[1][rr] + zsA[2][rr] + zsA[3][rr]);
    }
    __syncthreads();

    // ---- Phase B: thread (jsB, hB, q1) owns 8 features of head hB ----
    const int q1  = tid & 1;
    const int hB  = (tid >> 1) & 7;
    const int jsB = tid >> 4;             // 0..15
    const int fbase = hB * NHID + q1 * 8;
    const float ize0 = statE[0][hB], ize1 = statE[1][hB];
    const float izs0 = statS[0],     izs1 = statS[1];

    float acc0[8], acc1[8];
#pragma unroll
    for (int m = 0; m < 8; m++) { acc0[m] = 0.f; acc1[m] = 0.f; }
    float zt0 = 0.f, zt1 = 0.f;

#pragma unroll 2
    for (int tg = 0; tg < 16; tg++) {
        const int jg = tg * 16 + jsB;
        const int j0 = jg * 4;
        const float4 xq  = *(const float4*)&xLf[jg * XSTRIDE + hB * 4];
        const float4 e0q = *(const float4*)&evL[0][j0];
        const float4 e1q = *(const float4*)&evL[1][j0];
        const float xa[4]   = {xq.x, xq.y, xq.z, xq.w};
        const float ev0a[4] = {e0q.x, e0q.y, e0q.z, e0q.w};
        const float ev1a[4] = {e1q.x, e1q.y, e1q.z, e1q.w};
#pragma unroll
        for (int k = 0; k < 4; k++) {
            F2H u; u.f = xa[k];
            const float x0 = __low2float(u.h);
            const float x1 = __high2float(u.h);
            const float ev0 = ev0a[k], ev1 = ev1a[k];
            const float a0 = (ev0 != 0.f) ? fmaf(x0, ize0, ev0 * izs0) : 0.f;
            const float a1 = (ev1 != 0.f) ? fmaf(x1, ize1, ev1 * izs1) : 0.f;
            const float w0 = __expf(a0);     // exp(0)=1 at masked positions
            const float w1 = __expf(a1);
            zt0 += w0; zt1 += w1;
            const float4 gv = *(const float4*)(gh + (size_t)(j0 + k) * DIM + fbase);
            F2H g0, g1, g2, g3;
            g0.f = gv.x; g1.f = gv.y; g2.f = gv.z; g3.f = gv.w;
            const float2 p0 = __half22float2(g0.h);
            const float2 p1 = __half22float2(g1.h);
            const float2 p2 = __half22float2(g2.h);
            const float2 p3 = __half22float2(g3.h);
            acc0[0] = fmaf(w0, p0.x, acc0[0]); acc1[0] = fmaf(w1, p0.x, acc1[0]);
            acc0[1] = fmaf(w0, p0.y, acc0[1]); acc1[1] = fmaf(w1, p0.y, acc1[1]);
            acc0[2] = fmaf(w0, p1.x, acc0[2]); acc1[2] = fmaf(w1, p1.x, acc1[2]);
            acc0[3] = fmaf(w0, p1.y, acc0[3]); acc1[3] = fmaf(w1, p1.y, acc1[3]);
            acc0[4] = fmaf(w0, p2.x, acc0[4]); acc1[4] = fmaf(w1, p2.x, acc1[4]);
            acc0[5] = fmaf(w0, p2.y, acc0[5]); acc1[5] = fmaf(w1, p2.y, acc1[5]);
            acc0[6] = fmaf(w0, p3.x, acc0[6]); acc1[6] = fmaf(w1, p3.x, acc1[6]);
            acc0[7] = fmaf(w0, p3.y, acc0[7]); acc1[7] = fmaf(w1, p3.y, acc1[7]);
        }
    }

    // ---- Epilogue: reduce over jsB-in-wave (lane bits 4..5), then 4 waves ----
#pragma unroll
    for (int off = 16; off <= 32; off <<= 1) {
#pragma unroll
        for (int m = 0; m < 8; m++) {
            acc0[m] += __shfl_xor(acc0[m], off, 64);
            acc1[m] += __shfl_xor(acc1[m], off, 64);
        }
        zt0 += __shfl_xor(zt0, off, 64);
        zt1 += __shfl_xor(zt1, off, 64);
    }
    if (lane < 16) {
#pragma unroll
        for (int m = 0; m < 8; m++) {
            redO[wv][0][hB][q1][m] = acc0[m];
            redO[wv][1][hB][q1][m] = acc1[m];
        }
    }
    if ((lane & 0x31) == 0) {            // q1==0 && jsB-in-wave==0
        ztA[wv][0][hB] = zt0;
        ztA[wv][1][hB] = zt1;
    }
    __syncthreads();
    {
        const int rr = tid >> 7;
        const int hf = tid & 127;
        const int oh = hf >> 4;
        const int qq = (hf >> 3) & 1;
        const int f8 = hf & 7;
        const float v  = redO[0][rr][oh][qq][f8] + redO[1][rr][oh][qq][f8] +
                         redO[2][rr][oh][qq][f8] + redO[3][rr][oh][qq][f8];
        const float zq = ztA[0][rr][oh] + ztA[1][rr][oh] +
                         ztA[2][rr][oh] + ztA[3][rr][oh];
        out[(size_t)(i0 + rr) * DIM + hf] = v / zq;
    }
}

extern "C" void kernel_launch(void* const* d_in, const int* in_sizes, int n_in,
                              void* d_out, int out_size, void* d_ws, size_t ws_size,
                              hipStream_t stream) {
    const float* h      = (const float*)d_in[0];
    const int*   adj    = (const int*)  d_in[1];
    const float* s      = (const float*)d_in[2];
    const float* W      = (const float*)d_in[3];
    const float* attn_w = (const float*)d_in[4];
    float* out = (float*)d_out;

    __half* gh   = (__half*)d_ws;                         // 1024*128 fp16 = 256 KB
    float*  srcv = (float*)((char*)d_ws + (size_t)NNODES * DIM * sizeof(__half));
    float*  dstv = srcv + (size_t)NNODES * NHEADS;

    proj_kernel <<<NNODES, DIM, 0, stream>>>(h, W, attn_w, gh, srcv, dstv);
    fused_kernel<<<NNODES / 2, 256, 0, stream>>>(adj, s, gh, srcv, dstv, out);
}